// Round 1
// baseline (80.303 us; speedup 1.0000x reference)
//
#include <hip/hip_runtime.h>

// FidelityKernel: K[i,j] = |perm( (U2[j][:, :6])^H @ (U1[i][:, :6]) )|^2 / 1024
// Two-kernel split:
//   build_v: each of 4608 threads computes one (side, sample, column) gemv of
//            U(x) = A diag(e^{ix}) B, storing V-slices [2][384][12][6] complex
//            into d_ws (V2 stored conjugated). Each sample computed ONCE
//            (previously recomputed 24x inside every pair block).
//   pair_kernel: 48x48 grid of 64-thread blocks (8x8 pairs). Stage 16 V-rows
//            (9.2 KB) from L2 via float4, then one thread per pair runs the
//            6x6 complex W-build + Glynn permanent via 4 Gray-code chains.
//            Fine-grained grid (2304 blocks) removes the 576-block / 2-per-CU
//            quantization tail and raises resident waves for latency hiding.

typedef float v2f __attribute__((ext_vector_type(2)));

#define NS 384      // samples per side
#define MM 12       // modes
#define NP 6        // photons (submatrix size)
#define TSJ 8       // pair-tile edge (8x8 pairs per block = 64 threads)
#define VROW 144    // floats per sample row in global V (12 modes x 6 cols x 2)
#define SV_STRIDE 148  // LDS row stride: 144 payload + 4 pad (592B, 16B-aligned)

__device__ __forceinline__ v2f cmul(v2f a, v2f b) {
    v2f r = (v2f){a.x, a.x} * b;
    return __builtin_elementwise_fma((v2f){a.y, a.y}, (v2f){-b.y, b.x}, r);
}
__device__ __forceinline__ v2f cmac(v2f acc, v2f a, v2f b) {
    acc = __builtin_elementwise_fma((v2f){a.x, a.x}, b, acc);
    return __builtin_elementwise_fma((v2f){a.y, a.y}, (v2f){-b.y, b.x}, acc);
}

__device__ __forceinline__ v2f tree_prod(const v2f rs[NP]) {
    v2f p01 = cmul(rs[0], rs[1]);
    v2f p23 = cmul(rs[2], rs[3]);
    v2f p45 = cmul(rs[4], rs[5]);
    return cmul(cmul(p01, p23), p45);
}

// ---- Kernel 1: V-slice builder. 2*384*6 = 4608 jobs, one per thread.
__global__ __launch_bounds__(256) void build_v(const float* __restrict__ x1,
                                               const float* __restrict__ x2,
                                               const float* __restrict__ Ar,
                                               const float* __restrict__ Ai,
                                               const float* __restrict__ Br,
                                               const float* __restrict__ Bi,
                                               float* __restrict__ Vg) {
    const int job = blockIdx.x * 256 + threadIdx.x;
    if (job >= 2 * NS * NP) return;
    const int c = job % NP;
    const int s = (job / NP) % NS;
    const int half = job / (NS * NP);
    const float* x = half ? x2 : x1;

    // t[b] = e^{i x[s,b]} * B[b,c]
    v2f t[MM];
#pragma unroll
    for (int b = 0; b < MM; ++b) {
        float sv, cv;
        __sincosf(x[s * MM + b], &sv, &cv);   // hw v_sin/v_cos; x ~ N(0,1)
        v2f Bv = {Br[b * MM + c], Bi[b * MM + c]};
        t[b] = cmul((v2f){cv, sv}, Bv);
    }

    float* dst = Vg + (half * NS + s) * VROW;
    const float sgn = half ? -1.f : 1.f;      // conjugate V2 at store time
#pragma unroll
    for (int a = 0; a < MM; ++a) {
        v2f u = {0.f, 0.f};
#pragma unroll
        for (int b = 0; b < MM; ++b) {
            // A indices are wave-uniform -> scalar loads
            v2f Av = {Ar[a * MM + b], Ai[a * MM + b]};
            u = cmac(u, Av, t[b]);
        }
        dst[(a * NP + c) * 2]     = u.x;
        dst[(a * NP + c) * 2 + 1] = sgn * u.y;
    }
}

// ---- Kernel 2: one thread per (i,j) pair, 8x8 pairs per 64-thread block.
__global__ __launch_bounds__(64) void pair_kernel(const float* __restrict__ Vg,
                                                  float* __restrict__ out) {
    __shared__ __align__(16) float sV[2 * TSJ * SV_STRIDE];
    const int i0 = blockIdx.y * TSJ;
    const int j0 = blockIdx.x * TSJ;
    const int tid = threadIdx.x;

    // Stage 16 V-rows (rows 0..7 = V1[i0..], rows 8..15 = V2[j0..]) from L2.
    // 16 rows x 36 float4 = 576 chunks; 64 threads x 9 each.
#pragma unroll
    for (int q = 0; q < 9; ++q) {
        const int idx = q * 64 + tid;          // 0..575
        const int row = idx / 36;
        const int rem = idx - row * 36;
        const int half = row >> 3;
        const int s = half ? (NS + j0 + (row & 7)) : (i0 + (row & 7));
        const float4 v = ((const float4*)(Vg + s * VROW))[rem];
        *(float4*)(sV + row * SV_STRIDE + rem * 4) = v;
    }
    __syncthreads();

    const int tx = tid & (TSJ - 1), ty = tid >> 3;
    const float* v1 = sV + ty * SV_STRIDE;             // broadcast across tx
    const float* v2 = sV + (TSJ + tx) * SV_STRIDE;     // 8 rows, banks spread

    // W[a][b] = sum_k conj(U2[j,k,a]) * U1[i,k,b]  (conj baked into V2)
    v2f W[NP][NP];
#pragma unroll
    for (int a = 0; a < NP; ++a)
#pragma unroll
        for (int b = 0; b < NP; ++b) W[a][b] = (v2f){0.f, 0.f};

#pragma unroll
    for (int k = 0; k < MM; ++k) {
        const v2f* c1 = (const v2f*)(v1 + k * 12);
        const v2f* c2 = (const v2f*)(v2 + k * 12);
        v2f a1[NP], a2[NP];
#pragma unroll
        for (int b = 0; b < NP; ++b) { a1[b] = c1[b]; a2[b] = c2[b]; }
#pragma unroll
        for (int a = 0; a < NP; ++a)
#pragma unroll
            for (int b = 0; b < NP; ++b)
                W[a][b] = cmac(W[a][b], a2[a], a1[b]);
    }

    // Glynn: delta_0 = +1; bits s_0..s_4 <-> delta_1..delta_5.
    // Split on (s_3, s_4) -> 4 independent chains Gray-coding s_0..s_2.
    v2f base[NP];
#pragma unroll
    for (int b = 0; b < NP; ++b) {
        base[b] = W[0][b];
#pragma unroll
        for (int a = 1; a < NP; ++a) base[b] += W[a][b];
    }

    v2f rs[4][NP];
#pragma unroll
    for (int b = 0; b < NP; ++b) {
        v2f m2 = {-2.f, -2.f};
        rs[0][b] = base[b];
        rs[1][b] = __builtin_elementwise_fma(m2, W[4][b], base[b]);   // delta_4 = -1
        rs[2][b] = __builtin_elementwise_fma(m2, W[5][b], base[b]);   // delta_5 = -1
        rs[3][b] = __builtin_elementwise_fma(m2, W[5][b], rs[1][b]);  // both
    }
    // chain parity at u=0: (-1)^{s3+s4} = {+1, -1, -1, +1}
    v2f acc[4];
#pragma unroll
    for (int ch = 0; ch < 4; ++ch) acc[ch] = tree_prod(rs[ch]);

    unsigned st = 0;  // Gray state of s_0..s_2 (shared by all chains)
#pragma unroll
    for (int u = 1; u < 8; ++u) {
        const int bitpos = __builtin_ctz(u);   // compile-time after unroll
        const int r = bitpos + 1;              // row flipped (rows 1..3)
        float cf = ((st >> bitpos) & 1) ? 2.f : -2.f;
        st ^= (1u << bitpos);
        float sgn_u = (u & 1) ? -1.f : 1.f;    // (-1)^popcount(gray(u))
        v2f cfv = {cf, cf};
        v2f sgv = {sgn_u, sgn_u};
#pragma unroll
        for (int ch = 0; ch < 4; ++ch) {
#pragma unroll
            for (int b = 0; b < NP; ++b)
                rs[ch][b] = __builtin_elementwise_fma(cfv, W[r][b], rs[ch][b]);
            v2f p = tree_prod(rs[ch]);
            acc[ch] = __builtin_elementwise_fma(sgv, p, acc[ch]);
        }
    }

    v2f aa = acc[0] - acc[1] - acc[2] + acc[3];
    // perm = aa / 32; K = |perm|^2
    float K = fmaf(aa.x, aa.x, aa.y * aa.y) * (1.f / 1024.f);
    out[(i0 + ty) * NS + (j0 + tx)] = K;
}

extern "C" void kernel_launch(void* const* d_in, const int* in_sizes, int n_in,
                              void* d_out, int out_size, void* d_ws, size_t ws_size,
                              hipStream_t stream) {
    const float* x1 = (const float*)d_in[0];
    const float* x2 = (const float*)d_in[1];
    const float* Ar = (const float*)d_in[2];
    const float* Ai = (const float*)d_in[3];
    const float* Br = (const float*)d_in[4];
    const float* Bi = (const float*)d_in[5];
    float* out = (float*)d_out;
    float* Vg = (float*)d_ws;   // needs 2*384*144*4 = 442368 B

    build_v<<<dim3(18), 256, 0, stream>>>(x1, x2, Ar, Ai, Br, Bi, Vg);
    pair_kernel<<<dim3(NS / TSJ, NS / TSJ), 64, 0, stream>>>(Vg, out);
}

// Round 2
// 76.519 us; speedup vs baseline: 1.0495x; 1.0495x over previous
//
#include <hip/hip_runtime.h>

// FidelityKernel: K[i,j] = |perm( (U2[j][:, :6])^H @ (U1[i][:, :6]) )|^2 / 1024
//
// Key algebra: U(x) = A diag(e^{ix}) B with A unitary, so
//   W_ij = U2^H U1 = B6^H diag(e^{i(x1_i - x2_j)}) B6,   B6 = B[:, :6] (12x6)
// A cancels -> no 12x12 gemv anywhere. Per block we stage only the phase
// vectors e^{ix1} / conj(e^{ix2}) (sincos) and B6 / conj(B6) (1.1 KB) in LDS.
//
// Per pair: W[a][b] = sum_k conj(B[k,a]) * p_k * B[k,b], p_k = e1_k * e2c_k.
// Rolled k-loop (small code, broadcast LDS reads), then Glynn permanent via
// 2 Gray-code chains (split on delta_5; 16 steps each) -> low VGPR state.

typedef float v2f __attribute__((ext_vector_type(2)));

#define NS 384      // samples per side
#define MM 12       // modes
#define NP 6        // photons (submatrix size)
#define TSJ 8       // pair-tile edge (8x8 pairs per block = 64 threads)

__device__ __forceinline__ v2f cmul(v2f a, v2f b) {
    v2f r = (v2f){a.x, a.x} * b;
    return __builtin_elementwise_fma((v2f){a.y, a.y}, (v2f){-b.y, b.x}, r);
}
__device__ __forceinline__ v2f cmac(v2f acc, v2f a, v2f b) {
    acc = __builtin_elementwise_fma((v2f){a.x, a.x}, b, acc);
    return __builtin_elementwise_fma((v2f){a.y, a.y}, (v2f){-b.y, b.x}, acc);
}

__device__ __forceinline__ v2f tree_prod(const v2f rs[NP]) {
    v2f p01 = cmul(rs[0], rs[1]);
    v2f p23 = cmul(rs[2], rs[3]);
    v2f p45 = cmul(rs[4], rs[5]);
    return cmul(cmul(p01, p23), p45);
}

__global__ __launch_bounds__(64) void fused_kernel(const float* __restrict__ x1,
                                                   const float* __restrict__ x2,
                                                   const float* __restrict__ Br,
                                                   const float* __restrict__ Bi,
                                                   float* __restrict__ out) {
    // LDS: phase vectors for 8+8 samples, plus B6 and conj(B6). ~2.7 KB.
    __shared__ __align__(16) v2f sE1[TSJ * MM];    // e^{i x1[i0+r, m]}
    __shared__ __align__(16) v2f sE2[TSJ * MM];    // conj(e^{i x2[j0+r, m]})
    __shared__ __align__(16) v2f sB6[MM * NP];     // B[k, b],      b < 6
    __shared__ __align__(16) v2f sB6c[MM * NP];    // conj(B[k, b])

    const int i0 = blockIdx.y * TSJ;
    const int j0 = blockIdx.x * TSJ;
    const int tid = threadIdx.x;

    // ---- Phase 1a: 192 sincos jobs (16 samples x 12 modes), 3 per thread.
#pragma unroll
    for (int q = 0; q < 3; ++q) {
        const int idx = q * 64 + tid;              // 0..191
        const int half = idx >= TSJ * MM;
        const int rm = half ? idx - TSJ * MM : idx;
        const int r = rm / MM, m = rm - r * MM;
        const float xv = half ? x2[(j0 + r) * MM + m] : x1[(i0 + r) * MM + m];
        float sv, cv;
        __sincosf(xv, &sv, &cv);
        if (half) sE2[rm] = (v2f){cv, -sv};        // conjugate baked in
        else      sE1[rm] = (v2f){cv, sv};
    }
    // ---- Phase 1b: stage B6 and conj(B6). 72 entries, <=2 per thread.
#pragma unroll
    for (int q = 0; q < 2; ++q) {
        const int idx = q * 64 + tid;              // 0..127
        if (idx < MM * NP) {
            const int k = idx / NP, b = idx - k * NP;
            const float br = Br[k * MM + b];
            const float bi = Bi[k * MM + b];
            sB6[idx]  = (v2f){br, bi};
            sB6c[idx] = (v2f){br, -bi};
        }
    }
    __syncthreads();

    // ---- Phase 2: one thread per (i,j) pair.
    const int tx = tid & (TSJ - 1), ty = tid >> 3;
    const v2f* e1p = sE1 + ty * MM;    // 8 distinct addrs / wave (broadcast x8)
    const v2f* e2p = sE2 + tx * MM;

    v2f W[NP][NP];
#pragma unroll
    for (int a = 0; a < NP; ++a)
#pragma unroll
        for (int b = 0; b < NP; ++b) W[a][b] = (v2f){0.f, 0.f};

    // W[a][b] = sum_k conj(B[k,a]) * (p_k * B[k,b]);  rolled over k.
#pragma unroll 2
    for (int k = 0; k < MM; ++k) {
        const v2f p = cmul(e1p[k], e2p[k]);        // e^{i(x1-x2)} for mode k
        const v2f* Brow  = sB6  + k * NP;          // wave-uniform -> broadcast
        const v2f* Bcrow = sB6c + k * NP;
        v2f t[NP];
#pragma unroll
        for (int b = 0; b < NP; ++b) t[b] = cmul(p, Brow[b]);
#pragma unroll
        for (int a = 0; a < NP; ++a) {
            const v2f bc = Bcrow[a];
#pragma unroll
            for (int b = 0; b < NP; ++b)
                W[a][b] = cmac(W[a][b], bc, t[b]);
        }
    }

    // ---- Glynn permanent, 2 chains: delta_0 = +1; bits s_0..s_4 <-> delta_1..5.
    // Chain 0: s_4 = 0; chain 1: s_4 = 1 (delta_5 = -1). Gray-code s_0..s_3.
    v2f base[NP];
#pragma unroll
    for (int b = 0; b < NP; ++b) {
        base[b] = W[0][b];
#pragma unroll
        for (int a = 1; a < NP; ++a) base[b] += W[a][b];
    }

    v2f rs[2][NP];
#pragma unroll
    for (int b = 0; b < NP; ++b) {
        rs[0][b] = base[b];
        rs[1][b] = __builtin_elementwise_fma((v2f){-2.f, -2.f}, W[5][b], base[b]);
    }
    v2f acc[2];
    acc[0] = tree_prod(rs[0]);
    acc[1] = tree_prod(rs[1]);

    unsigned st = 0;  // Gray state of s_0..s_3 (shared by both chains)
#pragma unroll
    for (int u = 1; u < 16; ++u) {
        const int bitpos = __builtin_ctz(u);   // compile-time after unroll
        const int r = bitpos + 1;              // row flipped (rows 1..4)
        float cf = ((st >> bitpos) & 1) ? 2.f : -2.f;
        st ^= (1u << bitpos);
        float sgn_u = (u & 1) ? -1.f : 1.f;    // parity(popcount(gray(u))) = u&1
        v2f cfv = {cf, cf};
        v2f sgv = {sgn_u, sgn_u};
#pragma unroll
        for (int ch = 0; ch < 2; ++ch) {
#pragma unroll
            for (int b = 0; b < NP; ++b)
                rs[ch][b] = __builtin_elementwise_fma(cfv, W[r][b], rs[ch][b]);
            v2f p = tree_prod(rs[ch]);
            acc[ch] = __builtin_elementwise_fma(sgv, p, acc[ch]);
        }
    }

    // chain 1 carries the extra delta_5 = -1 parity factor.
    v2f aa = acc[0] - acc[1];
    // perm = aa / 32; K = |perm|^2
    float K = fmaf(aa.x, aa.x, aa.y * aa.y) * (1.f / 1024.f);
    out[(i0 + ty) * NS + (j0 + tx)] = K;
}

extern "C" void kernel_launch(void* const* d_in, const int* in_sizes, int n_in,
                              void* d_out, int out_size, void* d_ws, size_t ws_size,
                              hipStream_t stream) {
    const float* x1 = (const float*)d_in[0];
    const float* x2 = (const float*)d_in[1];
    // d_in[2], d_in[3] (A) are unused: A is unitary and cancels in U2^H U1.
    const float* Br = (const float*)d_in[4];
    const float* Bi = (const float*)d_in[5];
    float* out = (float*)d_out;
    (void)d_ws; (void)ws_size;

    fused_kernel<<<dim3(NS / TSJ, NS / TSJ), 64, 0, stream>>>(x1, x2, Br, Bi, out);
}